// Round 1
// 167.840 us; speedup vs baseline: 1.0447x; 1.0447x over previous
//
#include <hip/hip_runtime.h>
#include <math.h>

typedef unsigned short ushort_t;
typedef __bf16 v8bf __attribute__((ext_vector_type(8)));
typedef __bf16 v4bf __attribute__((ext_vector_type(4)));
typedef float  v4f  __attribute__((ext_vector_type(4)));
typedef float  f32x4 __attribute__((ext_vector_type(4)));

#define BATCH 4
#define SEQ 4096
#define DM 1024
#define NS 256
#define MROWS (BATCH*SEQ)   // 16384

#define NCH 128
#define CL (SEQ/NCH)        // 32

#define BK 32               // gemm2 K-step
#define BK1 64              // gemm1 K-step

typedef __attribute__((address_space(1))) void as1_void;
typedef __attribute__((address_space(3))) void as3_void;

__device__ __forceinline__ void gl_lds16(const void* g, void* l) {
    __builtin_amdgcn_global_load_lds((as1_void*)g, (as3_void*)l, 16, 0, 0);
}

__device__ __forceinline__ ushort_t f2bf(float f) {
    unsigned u = __builtin_bit_cast(unsigned, f);
    u += 0x7fff + ((u >> 16) & 1);          // RNE
    return (ushort_t)(u >> 16);
}

__device__ __forceinline__ float sigm(float x) { return 1.0f / (1.0f + expf(-x)); }

__device__ __forceinline__ float powk(int e, float l1, float l2, float l4,
                                      float l8, float l16) {
    float w = 1.0f;
    if (e & 1)  w *= l1;
    if (e & 2)  w *= l2;
    if (e & 4)  w *= l4;
    if (e & 8)  w *= l8;
    if (e & 16) w *= l16;
    return w;
}

// ---------------------------------------------------------------------------
// GEMM1 (full-K): Bu = u . B_w^T, tile 32(m) x 256(n), BK=64, double-buffered.
// grid = 512 blocks = 2/CU (LDS 72 KB -> 2 blocks/CU). Each block tile is
// exactly ONE scan chunk (32 rows), so the chunk-final
//   cf[b,c,n] = sum_t lam^(31-t) * Bu[t,n]
// is computed in-register from acc (no partials, no K-split summing).
// A staged fp32->bf16 via regs; B via global_load_lds.
// ---------------------------------------------------------------------------
__global__ __launch_bounds__(256)
void gemm1_fused(const float* __restrict__ A,      // u [M,K] fp32
                 const ushort_t* __restrict__ B,   // Bw16 [NS,K] bf16
                 float* __restrict__ Bu,           // [M,NS] fp32
                 const float* __restrict__ ll,     // [NS]
                 float* __restrict__ cf)           // [BATCH,NCH,NS]
{
    const int K = DM;
    __shared__ __align__(16) ushort_t As[2][32*BK1];    // 2 x 4 KB
    __shared__ __align__(16) ushort_t Bs[2][256*BK1];   // 2 x 32 KB

    const int tid  = threadIdx.x;
    const int lane = tid & 63;
    const int wave = tid >> 6;       // n-quadrant: cols wave*64..wave*64+63
    const int m0   = blockIdx.x * 32;

    const int fr = lane & 15;
    const int fq = lane >> 4;

    // A staging: 32x64 fp32 = 512 float4 chunks, 2/thread
    int arow[2], ac4[2];
    #pragma unroll
    for (int j = 0; j < 2; ++j) {
        int cid = j*256 + tid;
        arow[j] = cid >> 4;
        ac4[j]  = (cid & 15) * 4;
    }
    // B staging: 256x64 bf16 = 2048 x 16B chunks, 8/thread (lane-contig dst)
    int brow[8], bc[8];
    #pragma unroll
    for (int j = 0; j < 8; ++j) {
        int cid = j*256 + tid;
        brow[j] = cid >> 3;
        bc[j]   = (cid & 7) * 8;
    }

    f32x4 acc[2][4] = {};   // [mi][ni] : m = mi*16.., n = wave*64 + ni*16..
    v4f areg[2];

    // ---- prologue ----
    #pragma unroll
    for (int j = 0; j < 2; ++j)
        areg[j] = *(const v4f*)&A[(size_t)(m0 + arow[j])*K + ac4[j]];
    #pragma unroll
    for (int j = 0; j < 8; ++j)
        gl_lds16(&B[(size_t)brow[j]*K + bc[j]], &Bs[0][(j*256 + tid)*8]);

    const int NIT = K / BK1;   // 16
    for (int it = 0; it < NIT; ++it) {
        const int cur = it & 1;
        #pragma unroll
        for (int j = 0; j < 2; ++j)
            *(v4bf*)&As[cur][arow[j]*BK1 + ac4[j]] = __builtin_convertvector(areg[j], v4bf);
        __syncthreads();

        if (it + 1 < NIT) {
            const int k1 = (it + 1) * BK1;
            #pragma unroll
            for (int j = 0; j < 8; ++j)
                gl_lds16(&B[(size_t)brow[j]*K + k1 + bc[j]], &Bs[cur^1][(j*256 + tid)*8]);
            #pragma unroll
            for (int j = 0; j < 2; ++j)
                areg[j] = *(const v4f*)&A[(size_t)(m0 + arow[j])*K + k1 + ac4[j]];
        }

        #pragma unroll
        for (int kk = 0; kk < 2; ++kk) {
            v8bf af[2], bf[4];
            #pragma unroll
            for (int mi = 0; mi < 2; ++mi)
                af[mi] = *reinterpret_cast<const v8bf*>(
                    &As[cur][(mi*16 + fr)*BK1 + kk*32 + fq*8]);
            #pragma unroll
            for (int ni = 0; ni < 4; ++ni)
                bf[ni] = *reinterpret_cast<const v8bf*>(
                    &Bs[cur][(wave*64 + ni*16 + fr)*BK1 + kk*32 + fq*8]);

            #pragma unroll
            for (int mi = 0; mi < 2; ++mi)
                #pragma unroll
                for (int ni = 0; ni < 4; ++ni)
                    acc[mi][ni] = __builtin_amdgcn_mfma_f32_16x16x32_bf16(
                                      af[mi], bf[ni], acc[mi][ni], 0, 0, 0);
        }
    }

    // ---- write Bu. C/D layout: col=lane&15, row=(lane>>4)*4+reg ----
    #pragma unroll
    for (int mi = 0; mi < 2; ++mi) {
        #pragma unroll
        for (int ni = 0; ni < 4; ++ni) {
            const int col = wave*64 + ni*16 + fr;
            #pragma unroll
            for (int r = 0; r < 4; ++r)
                Bu[(size_t)(m0 + mi*16 + fq*4 + r)*NS + col] = acc[mi][ni][r];
        }
    }

    // ---- chunk final: cf[b,c,n] = sum_t lam^(31-t) Bu[t,n]; block = chunk ----
    const int b_idx = m0 >> 12;            // 4096 rows per batch
    const int c_idx = (m0 & 4095) >> 5;    // 32 rows per chunk

    #pragma unroll
    for (int ni = 0; ni < 4; ++ni) {
        const int col = wave*64 + ni*16 + fr;
        const float l1  = sigm(ll[col]);
        const float l2  = l1*l1;
        const float l4  = l2*l2;
        const float l8  = l4*l4;
        const float l16 = l8*l8;
        float f = 0.0f;
        #pragma unroll
        for (int mi = 0; mi < 2; ++mi) {
            // row t = mi*16 + fq*4 + r; weight lam^(31-t)
            float w = powk(28 - mi*16 - fq*4, l1, l2, l4, l8, l16);
            f = fmaf(w, acc[mi][ni][3], f);
            w *= l1; f = fmaf(w, acc[mi][ni][2], f);
            w *= l1; f = fmaf(w, acc[mi][ni][1], f);
            w *= l1; f = fmaf(w, acc[mi][ni][0], f);
        }
        f += __shfl_xor(f, 16, 64);
        f += __shfl_xor(f, 32, 64);
        if (fq == 0)
            cf[((size_t)b_idx*NCH + c_idx)*NS + col] = f;
    }
}

// ---------------------------------------------------------------------------
// GEMM2: y = hs . C_w^T (+ D*u per-element when D!=0).
// 128x128 tile, BK=32, dbuf, grid (8,128) = 1024 blocks = 4/CU.
// ---------------------------------------------------------------------------
__global__ __launch_bounds__(256)
void gemm2_mfma(const ushort_t* __restrict__ A,  // hs16 [M,256] bf16
                const ushort_t* __restrict__ B,  // Cw16 [1024,256] bf16
                float* __restrict__ C,           // y [M,1024] fp32
                const float* __restrict__ Dvec, const float* __restrict__ U)
{
    const int K = NS;
    const int N = DM;
    __shared__ __align__(16) ushort_t As[2][128*BK];
    __shared__ __align__(16) ushort_t Bs[2][128*BK];

    const int tid  = threadIdx.x;
    const int lane = tid & 63;
    const int wave = tid >> 6;
    const int wrow = wave >> 1;
    const int wcol = wave & 1;
    const int n0 = blockIdx.x * 128;
    const int m0 = blockIdx.y * 128;

    const int fr = lane & 15;
    const int fq = lane >> 4;

    f32x4 acc[4][4] = {};

    const int ch0 = wave*128 + lane;
    const int ch1 = ch0 + 64;
    const int r0 = ch0 >> 2, c0 = (ch0 & 3) * 8;
    const int r1 = ch1 >> 2, c1 = (ch1 & 3) * 8;

    gl_lds16(&A[(size_t)(m0 + r0)*K + c0], &As[0][ch0*8]);
    gl_lds16(&B[(size_t)(n0 + r0)*K + c0], &Bs[0][ch0*8]);
    gl_lds16(&A[(size_t)(m0 + r1)*K + c1], &As[0][ch1*8]);
    gl_lds16(&B[(size_t)(n0 + r1)*K + c1], &Bs[0][ch1*8]);

    for (int it = 0; it < K/BK; ++it) {
        const int cur = it & 1;
        __syncthreads();

        if (it + 1 < K/BK) {
            const int k1 = (it + 1) * BK;
            gl_lds16(&A[(size_t)(m0 + r0)*K + k1 + c0], &As[cur^1][ch0*8]);
            gl_lds16(&B[(size_t)(n0 + r0)*K + k1 + c0], &Bs[cur^1][ch0*8]);
            gl_lds16(&A[(size_t)(m0 + r1)*K + k1 + c1], &As[cur^1][ch1*8]);
            gl_lds16(&B[(size_t)(n0 + r1)*K + k1 + c1], &Bs[cur^1][ch1*8]);
        }

        v8bf af[4], bf[4];
        #pragma unroll
        for (int mi = 0; mi < 4; ++mi)
            af[mi] = *reinterpret_cast<const v8bf*>(&As[cur][(wrow*64 + mi*16 + fr)*BK + fq*8]);
        #pragma unroll
        for (int ni = 0; ni < 4; ++ni)
            bf[ni] = *reinterpret_cast<const v8bf*>(&Bs[cur][(wcol*64 + ni*16 + fr)*BK + fq*8]);

        #pragma unroll
        for (int mi = 0; mi < 4; ++mi)
            #pragma unroll
            for (int ni = 0; ni < 4; ++ni)
                acc[mi][ni] = __builtin_amdgcn_mfma_f32_16x16x32_bf16(
                                  af[mi], bf[ni], acc[mi][ni], 0, 0, 0);
    }

    const int orow = m0 + wrow*64 + (lane >> 4)*4;
    const int ocol = n0 + wcol*64 + (lane & 15);
    #pragma unroll
    for (int ni = 0; ni < 4; ++ni) {
        const int col = ocol + ni*16;
        const float d = Dvec[col];
        #pragma unroll
        for (int mi = 0; mi < 4; ++mi) {
            #pragma unroll
            for (int r = 0; r < 4; ++r) {
                const size_t idx = (size_t)(orow + mi*16 + r) * N + col;
                float v = acc[mi][ni][r];
                if (d != 0.0f) v = fmaf(d, U[idx], v);   // no load when D==0
                C[idx] = v;
            }
        }
    }
}

// ---------------------------------------------------------------------------
__global__ __launch_bounds__(256)
void cvt_w(const float4* __restrict__ Bw, const float4* __restrict__ Cw,
           ushort_t* __restrict__ Bo, ushort_t* __restrict__ Co)
{
    const int i = blockIdx.x * 256 + threadIdx.x;
    const float4* src = blockIdx.y ? Cw : Bw;
    ushort_t*     dst = blockIdx.y ? Co : Bo;
    float4 v = src[i];
    ushort4 o;
    o.x = f2bf(v.x); o.y = f2bf(v.y); o.z = f2bf(v.z); o.w = f2bf(v.w);
    *(ushort4*)&dst[4*(size_t)i] = o;
}

// ---------------------------------------------------------------------------
// Per-chunk scan with SELF-COMPUTED carry (replaces carry_scan + scan_apply):
// block (c,b): carry = sum_{c'<c} lamL^(c-1-c') cf[b,c',n] (Horner over the
// L2-resident cf buffer, <=128 coalesced loads), then replay the in-chunk
// recurrence on Bu and emit bf16 hs. grid (NCH, BATCH), blk=NS.
// ---------------------------------------------------------------------------
__global__ __launch_bounds__(256)
void scan_apply(const float* __restrict__ Bu, const float* __restrict__ ll,
                const float* __restrict__ cf, ushort_t* __restrict__ hs16)
{
    const int n = threadIdx.x, c = blockIdx.x, b = blockIdx.y;
    const float lam = sigm(ll[n]);
    float lamL = lam;
    #pragma unroll
    for (int i = 0; i < 5; ++i) lamL *= lamL;   // lam^32

    // ---- self carry: Horner over previous chunk finals ----
    const float* cfb = cf + (size_t)b*NCH*NS + n;
    float x = 0.0f;
    for (int c0 = 0; c0 < c; c0 += 16) {
        float v[16];
        #pragma unroll
        for (int j = 0; j < 16; ++j) {
            const int cc = c0 + j;
            v[j] = (cc < c) ? cfb[(size_t)cc*NS] : 0.0f;
        }
        #pragma unroll
        for (int j = 0; j < 16; ++j) {
            if (c0 + j < c) x = fmaf(lamL, x, v[j]);
        }
    }

    // ---- replay recurrence over the chunk ----
    const size_t base = ((size_t)b*SEQ + (size_t)c*CL)*NS + n;
    float v[CL];
    #pragma unroll
    for (int t = 0; t < CL; ++t)
        v[t] = Bu[base + (size_t)t*NS];

    float h = x;
    #pragma unroll
    for (int t = 0; t < CL; ++t) { h = fmaf(lam, h, v[t]); v[t] = h; }
    #pragma unroll
    for (int t = 0; t < CL; ++t) hs16[base + (size_t)t*NS] = f2bf(v[t]);
}

// ---------------------------------------------------------------------------
extern "C" void kernel_launch(void* const* d_in, const int* in_sizes, int n_in,
                              void* d_out, int out_size, void* d_ws, size_t ws_size,
                              hipStream_t stream) {
    const float* u          = (const float*)d_in[0];
    const float* log_lambda = (const float*)d_in[1];
    const float* B_w        = (const float*)d_in[2];
    const float* C_w        = (const float*)d_in[3];
    const float* Dv         = (const float*)d_in[4];
    float* y  = (float*)d_out;

    char* w = (char*)d_ws;
    float*    Bu    = (float*)w;                       // 16.78 MB
    ushort_t* hs16  = (ushort_t*)(w + 16777216);       // 8.39 MB
    ushort_t* Bw16  = (ushort_t*)(w + 25165824);       // 512 KB
    ushort_t* Cw16  = (ushort_t*)(w + 25690112);       // 512 KB
    float*    cf    = (float*)(w + 26214400);          // 512 KB

    dim3 blk(256);

    // 0) weight conversions
    cvt_w<<<dim3(256, 2), blk, 0, stream>>>((const float4*)B_w, (const float4*)C_w,
                                            Bw16, Cw16);

    // 1) Bu = u . B_w^T (full K), fused cvt + chunk finals
    gemm1_fused<<<dim3(MROWS/32), blk, 0, stream>>>(u, Bw16, Bu, log_lambda, cf);

    // 2) per-chunk scan with self-computed carry, emit bf16 hs
    scan_apply<<<dim3(NCH, BATCH), blk, 0, stream>>>(Bu, log_lambda, cf, hs16);

    // 3) y = hs . C_w^T + D*u
    gemm2_mfma<<<dim3(DM/128, MROWS/128), blk, 0, stream>>>(
        hs16, Cw16, y, Dv, u);
}